// Round 1
// baseline (1129.339 us; speedup 1.0000x reference)
//
#include <hip/hip_runtime.h>
#include <math.h>

#define N_BATCH 8
#define IN_CH   256
#define OUT_CH  256
#define T_LEN   2048
#define DKS     33
#define PAD     16
#define KC      16

#define OT 64   // out-channels per block
#define TT 64   // time positions per block

// ---------------------------------------------------------------------------
// Kernel 1: construct the dense conv kernel, stored TRANSPOSED as
// kern_t[i][d][o]  (so the conv kernel's LDS staging load is coalesced in o).
//
// Faithful to the reference ConstructKernel1d:
//   Pp = P + 16; p1 = floor(Pp[0,o,i,k]); frac = Pp[0,0,i,k]-floor(Pp[0,0,i,k])
//   (frac comes from OUT-CHANNEL 0 for every o — reproduced bug)
//   tap p1   += w*(1-frac)
//   tap p1+1 += w*frac      but ONLY if p1+1 <= 32 (I==P1+1 selects nothing
//                           when p1+1 == 33 — tap silently dropped)
// ---------------------------------------------------------------------------
__global__ void build_kern(const float* __restrict__ weight,
                           const float* __restrict__ P,
                           float* __restrict__ kern_t) {
    int idx = blockIdx.x * blockDim.x + threadIdx.x;   // o*IN_CH + i
    if (idx >= OUT_CH * IN_CH) return;
    int o = idx / IN_CH;
    int i = idx % IN_CH;

    float a[DKS];
#pragma unroll
    for (int d = 0; d < DKS; ++d) a[d] = 0.0f;

    const float* Po = P      + (size_t)(o * IN_CH + i) * KC;  // P[0,o,i,:]
    const float* P0 = P      + (size_t)(      i     ) * KC;   // P[0,0,i,:]
    const float* Wo = weight + (size_t)(o * IN_CH + i) * KC;

#pragma unroll
    for (int k = 0; k < KC; ++k) {
        float pp   = Po[k] + (float)(DKS / 2);   // in [0, 32]
        float p0   = P0[k] + (float)(DKS / 2);
        float frac = p0 - floorf(p0);            // out-channel 0's frac
        int   p1   = (int)floorf(pp);            // 0..32
        float w    = Wo[k];
        a[p1] += w * (1.0f - frac);
        if (p1 + 1 < DKS) a[p1 + 1] += w * frac;
    }

#pragma unroll
    for (int d = 0; d < DKS; ++d)
        kern_t[((size_t)i * DKS + d) * OUT_CH + o] = a[d];
}

// ---------------------------------------------------------------------------
// Kernel 2: the conv.  Grid (T/TT, OC/OT, N).  Block = 256 threads = 4 waves.
// Each thread computes a 4o x 4t register tile; per input channel we stage
// ks[d][o_local] (33*64 floats) and one 96-float x row in LDS.
// Inner loop: sliding x window (1 new LDS scalar/d) + float4 kern read,
// 16 v_fma_f32 per d.
// ---------------------------------------------------------------------------
__global__ __launch_bounds__(256) void dcls_conv(
    const float* __restrict__ x,
    const float* __restrict__ kern_t,
    const float* __restrict__ bias,
    float* __restrict__ out)
{
    __shared__ float ks[DKS * OT];        // [d][o_local], 8.25 KB
    __shared__ float xs[TT + 2 * PAD];    // 96 floats

    const int t0 = blockIdx.x * TT;
    const int o0 = blockIdx.y * OT;
    const int n  = blockIdx.z;

    const int tid = threadIdx.x;
    const int oq  = tid >> 4;      // 0..15
    const int tq  = tid & 15;      // 0..15
    const int ol  = oq * 4;        // local o base
    const int tl  = tq * 4;        // local t base

    float acc[4][4];
#pragma unroll
    for (int a = 0; a < 4; ++a)
#pragma unroll
        for (int b = 0; b < 4; ++b) acc[a][b] = 0.0f;

    for (int i = 0; i < IN_CH; ++i) {
        __syncthreads();   // previous iteration's reads done before overwrite

        // stage x row (with zero padding at the edges)
        if (tid < TT + 2 * PAD) {
            int g = t0 - PAD + tid;
            xs[tid] = (g >= 0 && g < T_LEN)
                        ? x[((size_t)n * IN_CH + i) * T_LEN + g] : 0.0f;
        }
        // stage kern tile, coalesced (kern_t is [i][d][o])
        const float* kp = kern_t + (size_t)i * DKS * OUT_CH + o0;
        for (int idx = tid; idx < DKS * OT; idx += 256) {
            int d   = idx >> 6;
            int olx = idx & 63;
            ks[idx] = kp[d * OUT_CH + olx];
        }
        __syncthreads();

        float xw0 = xs[tl + 0];
        float xw1 = xs[tl + 1];
        float xw2 = xs[tl + 2];
#pragma unroll
        for (int d = 0; d < DKS; ++d) {
            float xw3 = xs[tl + d + 3];
            const float4 kv = *reinterpret_cast<const float4*>(&ks[d * OT + ol]);
            acc[0][0] += kv.x * xw0; acc[0][1] += kv.x * xw1;
            acc[0][2] += kv.x * xw2; acc[0][3] += kv.x * xw3;
            acc[1][0] += kv.y * xw0; acc[1][1] += kv.y * xw1;
            acc[1][2] += kv.y * xw2; acc[1][3] += kv.y * xw3;
            acc[2][0] += kv.z * xw0; acc[2][1] += kv.z * xw1;
            acc[2][2] += kv.z * xw2; acc[2][3] += kv.z * xw3;
            acc[3][0] += kv.w * xw0; acc[3][1] += kv.w * xw1;
            acc[3][2] += kv.w * xw2; acc[3][3] += kv.w * xw3;
            xw0 = xw1; xw1 = xw2; xw2 = xw3;
        }
    }

    // epilogue: add bias, float4 stores (t0+tl is 16B aligned)
#pragma unroll
    for (int a = 0; a < 4; ++a) {
        int o = o0 + ol + a;
        float b = bias[o];
        float4 v = make_float4(acc[a][0] + b, acc[a][1] + b,
                               acc[a][2] + b, acc[a][3] + b);
        *reinterpret_cast<float4*>(
            &out[((size_t)n * OUT_CH + o) * T_LEN + t0 + tl]) = v;
    }
}

extern "C" void kernel_launch(void* const* d_in, const int* in_sizes, int n_in,
                              void* d_out, int out_size, void* d_ws, size_t ws_size,
                              hipStream_t stream) {
    const float* x      = (const float*)d_in[0];
    const float* weight = (const float*)d_in[1];
    const float* P      = (const float*)d_in[2];
    const float* bias   = (const float*)d_in[3];
    float*       out    = (float*)d_out;
    float*       kern_t = (float*)d_ws;   // 256*33*256 floats = 8.65 MB

    hipLaunchKernelGGL(build_kern,
                       dim3((OUT_CH * IN_CH + 255) / 256), dim3(256), 0, stream,
                       weight, P, kern_t);

    dim3 grid(T_LEN / TT, OUT_CH / OT, N_BATCH);
    hipLaunchKernelGGL(dcls_conv, grid, dim3(256), 0, stream,
                       x, kern_t, bias, out);
}

// Round 2
// 197.877 us; speedup vs baseline: 5.7073x; 5.7073x over previous
//
#include <hip/hip_runtime.h>
#include <math.h>

#define N_BATCH 8
#define IN_CH   256
#define OUT_CH  256
#define T_LEN   2048
#define DKS     33
#define PAD     16
#define KC      16

// conv tiling
#define MT 64      // out-channels per block
#define TT 128     // time per block (4 waves x 32)
#define XS_STRIDE 40   // Xs row stride in bf16 elements (80B, 16B-aligned)

typedef __attribute__((ext_vector_type(8))) short bf16x8;
typedef __attribute__((ext_vector_type(4))) float f32x4;

__device__ __forceinline__ unsigned short f2bf(float f) {
    unsigned u = __builtin_bit_cast(unsigned, f);
    unsigned r = (u + 0x7FFFu + ((u >> 16) & 1u)) >> 16;   // RNE
    return (unsigned short)r;
}

// ---------------------------------------------------------------------------
// Kernel 1: construct dense conv kernel in bf16, fragment-ready layout:
//   element (o,i,d) lives at
//   ((g*8 + c)*33 + d)*2048 + a*512 + l*8 + j
//   where g=o>>6, a=(o>>4)&3, m=o&15, c=i>>5, i_local=i&31,
//         quad=i_local>>3, j=i_local&7, l=quad*16+m.
//   So in the conv, lane l of a wave loads its A-frag (A[m=l&15][k=quad*8+j],
//   8 contiguous bf16 = 16B) with ONE coalesced global_load_dwordx4.
// Faithful reference semantics preserved: frac taken from out-channel 0,
// second tap dropped when p1+1 == 33.
// ---------------------------------------------------------------------------
__global__ void build_kern(const float* __restrict__ weight,
                           const float* __restrict__ P,
                           unsigned short* __restrict__ kern_f) {
    int idx = blockIdx.x * blockDim.x + threadIdx.x;   // o*IN_CH + i
    if (idx >= OUT_CH * IN_CH) return;
    int o = idx / IN_CH;
    int i = idx % IN_CH;

    float a[DKS];
#pragma unroll
    for (int d = 0; d < DKS; ++d) a[d] = 0.0f;

    const float* Po = P      + (size_t)(o * IN_CH + i) * KC;
    const float* P0 = P      + (size_t)i * KC;           // out-channel 0
    const float* Wo = weight + (size_t)(o * IN_CH + i) * KC;

#pragma unroll
    for (int k = 0; k < KC; ++k) {
        float pp   = Po[k] + (float)(DKS / 2);
        float p0   = P0[k] + (float)(DKS / 2);
        float frac = p0 - floorf(p0);
        int   p1   = (int)floorf(pp);
        float w    = Wo[k];
        a[p1] += w * (1.0f - frac);
        if (p1 + 1 < DKS) a[p1 + 1] += w * frac;
    }

    int g  = o >> 6;
    int ai = (o >> 4) & 3;
    int m  = o & 15;
    int c  = i >> 5;
    int il = i & 31;
    int q  = il >> 3;
    int j  = il & 7;
    size_t base = ((size_t)(g * 8 + c) * 33) * 2048
                + (size_t)ai * 512 + (size_t)(q * 16 + m) * 8 + j;
#pragma unroll
    for (int d = 0; d < DKS; ++d)
        kern_f[base + (size_t)d * 2048] = f2bf(a[d]);
}

// ---------------------------------------------------------------------------
// Kernel 2: implicit-GEMM conv with MFMA 16x16x32 bf16.
// Block: 256 thr = 4 waves. Block tile 64o x 128t; wave tile 64o x 32t.
// K-loop: 8 i-chunks of 32; inner d-loop of 33 (barrier-free).
// A-frags straight from global (L1/L2-hot, shared by all 4 waves).
// B from LDS Xs[t][i] (bf16, transposed during staging).
// ---------------------------------------------------------------------------
__global__ __launch_bounds__(256, 2) void dcls_conv(
    const float* __restrict__ x,
    const unsigned short* __restrict__ kern_f,
    const float* __restrict__ bias,
    float* __restrict__ out)
{
    __shared__ unsigned short Xs[(TT + 2 * PAD) * XS_STRIDE];  // 160*40*2B = 12.8KB

    const int t0    = blockIdx.x * TT;
    const int o0    = blockIdx.y * MT;
    const int batch = blockIdx.z;

    const int tid  = threadIdx.x;
    const int w    = tid >> 6;        // wave id 0..3
    const int l    = tid & 63;
    const int quad = l >> 4;
    const int lm   = l & 15;
    const int wt   = w * 32;          // wave's t base (local)

    f32x4 acc[4][2];
#pragma unroll
    for (int a = 0; a < 4; ++a)
#pragma unroll
        for (int b = 0; b < 2; ++b) acc[a][b] = (f32x4){0.f, 0.f, 0.f, 0.f};

    for (int c = 0; c < 8; ++c) {
        __syncthreads();   // previous chunk's reads done before overwrite

        // ---- stage Xs: 32 i x 160 t, transposed, fp32 -> bf16 (RNE) ----
        // thread handles (i-pair, t): global reads coalesced along t,
        // one packed b32 LDS write per thread per iter.
        const int i0 = c * 32;
#pragma unroll
        for (int it = 0; it < 10; ++it) {
            int idx = tid + it * 256;          // 0..2559
            int ip  = idx / 160;               // i-pair 0..15
            int t   = idx - ip * 160;          // 0..159
            int gg  = t0 - PAD + t;
            float v0 = 0.f, v1 = 0.f;
            if ((unsigned)gg < (unsigned)T_LEN) {
                const float* xb = x + ((size_t)(batch * IN_CH + i0 + ip * 2) * T_LEN) + gg;
                v0 = xb[0];
                v1 = xb[T_LEN];
            }
            unsigned pk = (unsigned)f2bf(v0) | ((unsigned)f2bf(v1) << 16);
            *(unsigned*)(&Xs[t * XS_STRIDE + ip * 2]) = pk;
        }
        __syncthreads();

        // ---- 33 barrier-free K-steps over d ----
        const unsigned short* kf = kern_f
            + ((size_t)(blockIdx.y * 8 + c) * 33) * 2048 + (size_t)l * 8;

        for (int d = 0; d < DKS; ++d) {
            bf16x8 af[4];
#pragma unroll
            for (int a = 0; a < 4; ++a)
                af[a] = *(const bf16x8*)(kf + (size_t)d * 2048 + a * 512);
            bf16x8 bf[2];
#pragma unroll
            for (int b = 0; b < 2; ++b)
                bf[b] = *(const bf16x8*)(&Xs[(wt + b * 16 + lm + d) * XS_STRIDE + quad * 8]);
#pragma unroll
            for (int a = 0; a < 4; ++a)
#pragma unroll
                for (int b = 0; b < 2; ++b)
                    acc[a][b] = __builtin_amdgcn_mfma_f32_16x16x32_bf16(
                        af[a], bf[b], acc[a][b], 0, 0, 0);
        }
    }

    // ---- epilogue: bias + fp32 stores ----
#pragma unroll
    for (int a = 0; a < 4; ++a) {
#pragma unroll
        for (int r = 0; r < 4; ++r) {
            int o = o0 + a * 16 + quad * 4 + r;
            float bv = bias[o];
            float* orow = out + ((size_t)(batch * OUT_CH + o) * T_LEN) + t0 + wt + lm;
#pragma unroll
            for (int b = 0; b < 2; ++b)
                orow[b * 16] = acc[a][b][r] + bv;
        }
    }
}

extern "C" void kernel_launch(void* const* d_in, const int* in_sizes, int n_in,
                              void* d_out, int out_size, void* d_ws, size_t ws_size,
                              hipStream_t stream) {
    const float* x      = (const float*)d_in[0];
    const float* weight = (const float*)d_in[1];
    const float* P      = (const float*)d_in[2];
    const float* bias   = (const float*)d_in[3];
    float*       out    = (float*)d_out;
    unsigned short* kern_f = (unsigned short*)d_ws;   // 256*256*33 bf16 = 4.33MB

    hipLaunchKernelGGL(build_kern,
                       dim3((OUT_CH * IN_CH + 255) / 256), dim3(256), 0, stream,
                       weight, P, kern_f);

    dim3 grid(T_LEN / TT, OUT_CH / MT, N_BATCH);
    hipLaunchKernelGGL(dcls_conv, grid, dim3(256), 0, stream,
                       x, kern_f, bias, out);
}